// Round 3
// baseline (907.556 us; speedup 1.0000x reference)
//
#include <hip/hip_runtime.h>
#include <hip/hip_bf16.h>
#include <cstdint>
#include <math.h>

#define NB 4
#define NN 512
#define DH 128
#define NHEADS 8
#define NHID 16
#define SLOPE 0.2f
#define TI 2
#define SATT 520   // head-row stride: 2*520 % 32 == 16 -> fq groups alias 2-way (free)

// Projection: 4 node-rows per block (512 blocks -> 2/CU, 8 waves/CU).
// t<128 -> gl (Wl), t>=128 -> gr (Wr). 8-deep W-load batches for ILP.
__global__ __launch_bounds__(256) void proj_kernel(
    const float* __restrict__ h, const float* __restrict__ X,
    const float* __restrict__ Win,
    const float* __restrict__ Wl, const float* __restrict__ Wr,
    float* __restrict__ gl, float* __restrict__ gr)
{
    __shared__ __align__(16) float s_h[4][DH];
    const int bn0 = blockIdx.x * 4;
    const int t = threadIdx.x;

    if (X) {
        if (t < DH) {
            const float w0 = Win[t], w1 = Win[DH + t];
#pragma unroll
            for (int r = 0; r < 4; ++r) {
                const float x0 = X[(bn0 + r) * 2 + 0];
                const float x1 = X[(bn0 + r) * 2 + 1];
                s_h[r][t] = x0 * w0 + x1 * w1;
            }
        }
    } else {
        for (int idx = t; idx < 4 * DH; idx += 256)
            s_h[idx >> 7][idx & 127] = h[(size_t)bn0 * DH + idx];
    }
    __syncthreads();

    const float* W = (t < DH) ? Wl : Wr;   // wave-uniform split
    float*       g = (t < DH) ? gl : gr;
    const int f = t & 127;
    float acc[4] = {};
    for (int k = 0; k < DH; k += 8) {
        float w[8];
#pragma unroll
        for (int u = 0; u < 8; ++u) w[u] = W[(k + u) * DH + f];   // 8 loads in flight
#pragma unroll
        for (int r = 0; r < 4; ++r) {
            const float4 h0 = *(const float4*)&s_h[r][k];
            const float4 h1 = *(const float4*)&s_h[r][k + 4];
            acc[r] += h0.x * w[0] + h0.y * w[1] + h0.z * w[2] + h0.w * w[3]
                    + h1.x * w[4] + h1.y * w[5] + h1.z * w[6] + h1.w * w[7];
        }
    }
#pragma unroll
    for (int r = 0; r < 4; ++r)
        g[((size_t)bn0 + r) * DH + f] = acc[r];
}

// One block per (b, 2 query rows). 512 threads, 33.3KB LDS -> 4 blocks/CU.
// A: thread (jj=t>>2, fq=t&3) owns heads {2fq,2fq+1} for 4 j-groups; each
//    head-pair load is one 64B line (coalesced within thread, L1-friendly).
// B: wave w -> softmax rows 2w, 2w+1.
// C: thread (f0=(t&31)*4, q=t>>5): float4 gr loads, 2 rows x 512B/wave-instr.
__global__ __launch_bounds__(512, 8) void attn_kernel(
    const float* __restrict__ gl, const float* __restrict__ gr,
    const int* __restrict__ adj, const float* __restrict__ a_vec,
    float* __restrict__ h_out,
    const float* __restrict__ Wout, float* __restrict__ out)
{
    __shared__ float s_att[TI * NHEADS * SATT];          // 33280 B
    __shared__ __align__(16) float s_gri[TI * DH];
    __shared__ float s_out[TI * DH];
    __shared__ __align__(16) float s_a[NHID];

    const int blk = blockIdx.x;          // 0..1023
    const int b   = blk & 3;             // XCD swizzle: batch b lives on 2 XCDs
    const int i0  = (blk >> 2) * TI;
    const int t   = threadIdx.x;

    {   // stage gr rows for the 2 queries + a + zero output accumulator
        if (t < TI * DH) s_gri[t] = gr[((size_t)(b * NN + i0)) * DH + t];
        if (t < TI * DH) s_out[t] = 0.f;
        if (t < NHID)    s_a[t]   = a_vec[t];
    }
    __syncthreads();

    // ---- Phase A: scores ----
    {
        const int jj = t >> 2;           // 0..127
        const int fq = t & 3;            // head pair {2fq, 2fq+1}
        const float4* a4 = (const float4*)s_a;
#pragma unroll
        for (int jt = 0; jt < 4; ++jt) {
            const int j = jt * 128 + jj;
            const int m0 = adj[((size_t)b << 18) + ((size_t)i0 << 9) + j];
            const int m1 = adj[((size_t)b << 18) + ((size_t)(i0 + 1) << 9) + j];
            const float4* gp = (const float4*)(gl + ((size_t)(b * NN + j)) * DH + fq * 32);
#pragma unroll
            for (int hs = 0; hs < 2; ++hs) {
                const int hh = 2 * fq + hs;
                float4 G[4];
#pragma unroll
                for (int q = 0; q < 4; ++q) G[q] = gp[hs * 4 + q];  // one 64B line
#pragma unroll
                for (int ti = 0; ti < TI; ++ti) {
                    const float4* r4 = (const float4*)(s_gri + ti * DH + hh * NHID);
                    float s = 0.f;
#pragma unroll
                    for (int q = 0; q < 4; ++q) {
                        const float4 g = G[q], r = r4[q], av = a4[q];
                        float v;
                        v = g.x + r.x; v = fmaxf(v, SLOPE * v); s += v * av.x;
                        v = g.y + r.y; v = fmaxf(v, SLOPE * v); s += v * av.y;
                        v = g.z + r.z; v = fmaxf(v, SLOPE * v); s += v * av.z;
                        v = g.w + r.w; v = fmaxf(v, SLOPE * v); s += v * av.w;
                    }
                    const int m = ti ? m1 : m0;
                    s_att[(ti * NHEADS + hh) * SATT + j] = m ? s : -INFINITY;
                }
            }
        }
    }
    __syncthreads();

    // ---- Phase B: softmax over j; 16 rows, 2 per wave ----
    {
        const int wv = t >> 6, lane = t & 63;
#pragma unroll
        for (int p = 0; p < 2; ++p) {
            float* row = s_att + (wv * 2 + p) * SATT;
            float e[8];
            float m = -INFINITY;
#pragma unroll
            for (int k = 0; k < 8; ++k) { e[k] = row[lane + (k << 6)]; m = fmaxf(m, e[k]); }
#pragma unroll
            for (int off = 32; off; off >>= 1) m = fmaxf(m, __shfl_xor(m, off));
            float sum = 0.f;
#pragma unroll
            for (int k = 0; k < 8; ++k) { e[k] = __expf(e[k] - m); sum += e[k]; }
#pragma unroll
            for (int off = 32; off; off >>= 1) sum += __shfl_xor(sum, off);
            const float inv = 1.f / sum;
#pragma unroll
            for (int k = 0; k < 8; ++k) row[lane + (k << 6)] = e[k] * inv;
        }
    }
    __syncthreads();

    // ---- Phase C: out[ti][f] = sum_j att[ti][h(f)][j] * gr[b,j,f] ----
    {
        const int f0 = (t & 31) << 2;
        const int hh = f0 >> 4;
        const int q  = t >> 5;               // j-group 0..15 (32 j each)
        const float* gp  = gr + ((size_t)(b * NN + q * 32)) * DH + f0;
        const float* ar0 = s_att + hh * SATT + q * 32;
        const float* ar1 = ar0 + NHEADS * SATT;
        float4 acc0 = {}, acc1 = {};
#pragma unroll 8
        for (int jj = 0; jj < 32; ++jj) {
            const float4 g = *(const float4*)(gp + (size_t)jj * DH);  // 2 rows/wave-instr
            const float a0 = ar0[jj], a1 = ar1[jj];                   // broadcast
            acc0.x += a0 * g.x; acc0.y += a0 * g.y; acc0.z += a0 * g.z; acc0.w += a0 * g.w;
            acc1.x += a1 * g.x; acc1.y += a1 * g.y; acc1.z += a1 * g.z; acc1.w += a1 * g.w;
        }
        atomicAdd(&s_out[f0 + 0], acc0.x); atomicAdd(&s_out[f0 + 1], acc0.y);
        atomicAdd(&s_out[f0 + 2], acc0.z); atomicAdd(&s_out[f0 + 3], acc0.w);
        atomicAdd(&s_out[DH + f0 + 0], acc1.x); atomicAdd(&s_out[DH + f0 + 1], acc1.y);
        atomicAdd(&s_out[DH + f0 + 2], acc1.z); atomicAdd(&s_out[DH + f0 + 3], acc1.w);
    }
    __syncthreads();

    if (Wout) {                              // fused final h @ W_out
        if (t < TI * 64) {
            const int ti = t >> 6, lane = t & 63;
            float v = s_out[ti * DH + lane]      * Wout[lane]
                    + s_out[ti * DH + lane + 64] * Wout[lane + 64];
#pragma unroll
            for (int off = 32; off; off >>= 1) v += __shfl_xor(v, off);
            if (lane == 0) out[b * NN + i0 + ti] = v;
        }
    } else {
        if (t < TI * DH)
            h_out[((size_t)(b * NN + i0)) * DH + t] = s_out[t];
    }
}

extern "C" void kernel_launch(void* const* d_in, const int* in_sizes, int n_in,
                              void* d_out, int out_size, void* d_ws, size_t ws_size,
                              hipStream_t stream) {
    const float* X    = (const float*)d_in[0];   // [4,512,2]
    const int*   adj  = (const int*)  d_in[1];   // [4,512,512]
    const float* Win  = (const float*)d_in[2];   // [2,128]
    const float* Wl   = (const float*)d_in[3];   // [3,128,128]
    const float* Wr   = (const float*)d_in[4];   // [3,128,128]
    const float* Aa   = (const float*)d_in[5];   // [3,16]
    const float* Wout = (const float*)d_in[6];   // [128,1]
    float* out = (float*)d_out;                  // [4,512] fp32

    float* ws = (float*)d_ws;
    float* h  = ws;                // 1 MB
    float* gl = ws + 262144;       // 1 MB
    float* gr = ws + 524288;       // 1 MB

    for (int l = 0; l < 3; ++l) {
        proj_kernel<<<NB * NN / 4, 256, 0, stream>>>(
            h, (l == 0) ? X : nullptr, Win,
            Wl + (size_t)l * DH * DH, Wr + (size_t)l * DH * DH, gl, gr);
        const bool last = (l == 2);
        attn_kernel<<<NB * NN / TI, 512, 0, stream>>>(
            gl, gr, adj, Aa + l * NHID, h,
            last ? Wout : nullptr, out);
    }
}

// Round 4
// 327.243 us; speedup vs baseline: 2.7733x; 2.7733x over previous
//
#include <hip/hip_runtime.h>
#include <hip/hip_bf16.h>
#include <cstdint>
#include <math.h>

#define NB 4
#define NN 512
#define DH 128
#define NHEADS 8
#define NHID 16
#define SLOPE 0.2f
#define TI 2
#define SATT 520   // head-row stride (words): fq groups alias 2-way in Phase A (free)

// Projection: 2 node-rows per block (1024 blocks -> 4/CU, 16 waves/CU).
// t<128 -> gl (Wl), t>=128 -> gr (Wr). 8-deep W-load batches for ILP.
__global__ __launch_bounds__(256) void proj_kernel(
    const float* __restrict__ h, const float* __restrict__ X,
    const float* __restrict__ Win,
    const float* __restrict__ Wl, const float* __restrict__ Wr,
    float* __restrict__ gl, float* __restrict__ gr)
{
    __shared__ __align__(16) float s_h[2][DH];
    const int bn0 = blockIdx.x * 2;
    const int t = threadIdx.x;

    if (X) {
        if (t < DH) {
            const float w0 = Win[t], w1 = Win[DH + t];
#pragma unroll
            for (int r = 0; r < 2; ++r) {
                const float x0 = X[(bn0 + r) * 2 + 0];
                const float x1 = X[(bn0 + r) * 2 + 1];
                s_h[r][t] = x0 * w0 + x1 * w1;
            }
        }
    } else {
        if (t < 2 * DH)
            s_h[t >> 7][t & 127] = h[(size_t)bn0 * DH + t];
    }
    __syncthreads();

    const float* W = (t < DH) ? Wl : Wr;   // wave-uniform split
    float*       g = (t < DH) ? gl : gr;
    const int f = t & 127;
    float acc0 = 0.f, acc1 = 0.f;
    for (int k = 0; k < DH; k += 8) {
        float w[8];
#pragma unroll
        for (int u = 0; u < 8; ++u) w[u] = W[(k + u) * DH + f];   // 8 loads in flight
        const float4 a0 = *(const float4*)&s_h[0][k];
        const float4 a1 = *(const float4*)&s_h[0][k + 4];
        const float4 b0 = *(const float4*)&s_h[1][k];
        const float4 b1 = *(const float4*)&s_h[1][k + 4];
        acc0 += a0.x * w[0] + a0.y * w[1] + a0.z * w[2] + a0.w * w[3]
              + a1.x * w[4] + a1.y * w[5] + a1.z * w[6] + a1.w * w[7];
        acc1 += b0.x * w[0] + b0.y * w[1] + b0.z * w[2] + b0.w * w[3]
              + b1.x * w[4] + b1.y * w[5] + b1.z * w[6] + b1.w * w[7];
    }
    g[((size_t)bn0 + 0) * DH + f] = acc0;
    g[((size_t)bn0 + 1) * DH + f] = acc1;
}

// One block per (b, 2 query rows). 512 threads, ~36KB LDS -> 4 blocks/CU capacity.
// A: thread (jj=t>>2, fq=t&3) owns heads {2fq,2fq+1}; 64B-line gl loads.
// B: wave w -> softmax rows 2w, 2w+1.
// C: thread (f0=(t&31)*4, q=t>>5): float4 gr loads, LDS atomic reduce.
__global__ __launch_bounds__(512) void attn_kernel(
    const float* __restrict__ gl, const float* __restrict__ gr,
    const int* __restrict__ adj, const float* __restrict__ a_vec,
    float* __restrict__ h_out,
    const float* __restrict__ Wout, float* __restrict__ out)
{
    __shared__ float s_att[TI * NHEADS * SATT];          // 33280 B
    __shared__ __align__(16) float s_gri[TI * DH];
    __shared__ float s_out[TI * DH];
    __shared__ __align__(16) float s_a[NHID];

    const int blk = blockIdx.x;          // 0..1023
    const int b   = blk & 3;             // XCD swizzle: batch b pinned to 2 XCDs
    const int i0  = (blk >> 2) * TI;
    const int t   = threadIdx.x;

    {   // stage gr rows for the 2 queries + a + zero output accumulator
        if (t < TI * DH) { s_gri[t] = gr[((size_t)(b * NN + i0)) * DH + t]; s_out[t] = 0.f; }
        if (t < NHID)    s_a[t] = a_vec[t];
    }
    __syncthreads();

    // ---- Phase A: scores ----
    {
        const int jj = t >> 2;           // 0..127
        const int fq = t & 3;            // head pair {2fq, 2fq+1}
        const float4* a4 = (const float4*)s_a;
#pragma unroll
        for (int jt = 0; jt < 4; ++jt) {
            const int j = jt * 128 + jj;
            const int m0 = adj[((size_t)b << 18) + ((size_t)i0 << 9) + j];
            const int m1 = adj[((size_t)b << 18) + ((size_t)(i0 + 1) << 9) + j];
            const float4* gp = (const float4*)(gl + ((size_t)(b * NN + j)) * DH + fq * 32);
#pragma unroll
            for (int hs = 0; hs < 2; ++hs) {
                const int hh = 2 * fq + hs;
                float4 G[4];
#pragma unroll
                for (int q = 0; q < 4; ++q) G[q] = gp[hs * 4 + q];  // one 64B line
#pragma unroll
                for (int ti = 0; ti < TI; ++ti) {
                    const float4* r4 = (const float4*)(s_gri + ti * DH + hh * NHID);
                    float s = 0.f;
#pragma unroll
                    for (int q = 0; q < 4; ++q) {
                        const float4 g = G[q], r = r4[q], av = a4[q];
                        float v;
                        v = g.x + r.x; v = fmaxf(v, SLOPE * v); s += v * av.x;
                        v = g.y + r.y; v = fmaxf(v, SLOPE * v); s += v * av.y;
                        v = g.z + r.z; v = fmaxf(v, SLOPE * v); s += v * av.z;
                        v = g.w + r.w; v = fmaxf(v, SLOPE * v); s += v * av.w;
                    }
                    const int m = ti ? m1 : m0;
                    s_att[(ti * NHEADS + hh) * SATT + j] = m ? s : -INFINITY;
                }
            }
        }
    }
    __syncthreads();

    // ---- Phase B: softmax over j; 16 rows, 2 per wave ----
    {
        const int wv = t >> 6, lane = t & 63;
#pragma unroll
        for (int p = 0; p < 2; ++p) {
            float* row = s_att + (wv * 2 + p) * SATT;
            float e[8];
            float m = -INFINITY;
#pragma unroll
            for (int k = 0; k < 8; ++k) { e[k] = row[lane + (k << 6)]; m = fmaxf(m, e[k]); }
#pragma unroll
            for (int off = 32; off; off >>= 1) m = fmaxf(m, __shfl_xor(m, off));
            float sum = 0.f;
#pragma unroll
            for (int k = 0; k < 8; ++k) { e[k] = __expf(e[k] - m); sum += e[k]; }
#pragma unroll
            for (int off = 32; off; off >>= 1) sum += __shfl_xor(sum, off);
            const float inv = 1.f / sum;
#pragma unroll
            for (int k = 0; k < 8; ++k) row[lane + (k << 6)] = e[k] * inv;
        }
    }
    __syncthreads();

    // ---- Phase C: out[ti][f] = sum_j att[ti][h(f)][j] * gr[b,j,f] ----
    {
        const int f0 = (t & 31) << 2;
        const int hh = f0 >> 4;
        const int q  = t >> 5;               // j-group 0..15 (32 j each)
        const float* gp  = gr + ((size_t)(b * NN + q * 32)) * DH + f0;
        const float* ar0 = s_att + hh * SATT + q * 32;
        const float* ar1 = ar0 + NHEADS * SATT;
        float4 acc0 = {}, acc1 = {};
#pragma unroll 8
        for (int jj = 0; jj < 32; ++jj) {
            const float4 g = *(const float4*)(gp + (size_t)jj * DH);
            const float a0 = ar0[jj], a1 = ar1[jj];                   // broadcast
            acc0.x += a0 * g.x; acc0.y += a0 * g.y; acc0.z += a0 * g.z; acc0.w += a0 * g.w;
            acc1.x += a1 * g.x; acc1.y += a1 * g.y; acc1.z += a1 * g.z; acc1.w += a1 * g.w;
        }
        atomicAdd(&s_out[f0 + 0], acc0.x); atomicAdd(&s_out[f0 + 1], acc0.y);
        atomicAdd(&s_out[f0 + 2], acc0.z); atomicAdd(&s_out[f0 + 3], acc0.w);
        atomicAdd(&s_out[DH + f0 + 0], acc1.x); atomicAdd(&s_out[DH + f0 + 1], acc1.y);
        atomicAdd(&s_out[DH + f0 + 2], acc1.z); atomicAdd(&s_out[DH + f0 + 3], acc1.w);
    }
    __syncthreads();

    if (Wout) {                              // fused final h @ W_out
        if (t < TI * 64) {
            const int ti = t >> 6, lane = t & 63;
            float v = s_out[ti * DH + lane]      * Wout[lane]
                    + s_out[ti * DH + lane + 64] * Wout[lane + 64];
#pragma unroll
            for (int off = 32; off; off >>= 1) v += __shfl_xor(v, off);
            if (lane == 0) out[b * NN + i0 + ti] = v;
        }
    } else {
        if (t < TI * DH)
            h_out[((size_t)(b * NN + i0)) * DH + t] = s_out[t];
    }
}

extern "C" void kernel_launch(void* const* d_in, const int* in_sizes, int n_in,
                              void* d_out, int out_size, void* d_ws, size_t ws_size,
                              hipStream_t stream) {
    const float* X    = (const float*)d_in[0];   // [4,512,2]
    const int*   adj  = (const int*)  d_in[1];   // [4,512,512]
    const float* Win  = (const float*)d_in[2];   // [2,128]
    const float* Wl   = (const float*)d_in[3];   // [3,128,128]
    const float* Wr   = (const float*)d_in[4];   // [3,128,128]
    const float* Aa   = (const float*)d_in[5];   // [3,16]
    const float* Wout = (const float*)d_in[6];   // [128,1]
    float* out = (float*)d_out;                  // [4,512] fp32

    float* ws = (float*)d_ws;
    float* h  = ws;                // 1 MB
    float* gl = ws + 262144;       // 1 MB
    float* gr = ws + 524288;       // 1 MB

    for (int l = 0; l < 3; ++l) {
        proj_kernel<<<NB * NN / 2, 256, 0, stream>>>(
            h, (l == 0) ? X : nullptr, Win,
            Wl + (size_t)l * DH * DH, Wr + (size_t)l * DH * DH, gl, gr);
        const bool last = (l == 2);
        attn_kernel<<<NB * NN / TI, 512, 0, stream>>>(
            gl, gr, adj, Aa + l * NHID, h,
            last ? Wout : nullptr, out);
    }
}

// Round 5
// 181.050 us; speedup vs baseline: 5.0127x; 1.8075x over previous
//
#include <hip/hip_runtime.h>
#include <hip/hip_bf16.h>
#include <cstdint>
#include <math.h>

#define NB 4
#define NN 512
#define DH 128
#define NHEADS 8
#define NHID 16
#define SLOPE 0.2f
#define ITILE 32
#define SENTINEL -1e30f

// ---- one-time adjacency bitmask pack: adjb[row][w] bit k = adj[row][w*32+k] ----
__global__ __launch_bounds__(256) void pack_adj_kernel(
    const int* __restrict__ adj, uint32_t* __restrict__ adjb)
{
    const int t   = threadIdx.x;
    const int row = blockIdx.x * 16 + (t >> 4);
    const int w   = t & 15;
    const int4* p = (const int4*)(adj + (size_t)row * NN + w * 32);
    uint32_t m = 0;
#pragma unroll
    for (int c = 0; c < 8; ++c) {
        const int4 v = p[c];
        m |= (v.x != 0 ? 1u : 0u) << (c * 4 + 0);
        m |= (v.y != 0 ? 1u : 0u) << (c * 4 + 1);
        m |= (v.z != 0 ? 1u : 0u) << (c * 4 + 2);
        m |= (v.w != 0 ? 1u : 0u) << (c * 4 + 3);
    }
    adjb[(size_t)row * 16 + w] = m;
}

// ---- projection: 8 rows/block, outputs HEAD-MAJOR gl/gr [b*8+hh][512][16] ----
__global__ __launch_bounds__(256) void proj_kernel(
    const float* __restrict__ h, const float* __restrict__ X,
    const float* __restrict__ Win,
    const float* __restrict__ Wl, const float* __restrict__ Wr,
    float* __restrict__ gl, float* __restrict__ gr)
{
    __shared__ __align__(16) float s_h[8][DH];
    const int bn0 = blockIdx.x * 8;
    const int b   = bn0 >> 9;
    const int n0  = bn0 & 511;
    const int t   = threadIdx.x;

    if (X) {
        if (t < DH) {
            const float w0 = Win[t], w1 = Win[DH + t];
#pragma unroll
            for (int r = 0; r < 8; ++r) {
                const float x0 = X[(bn0 + r) * 2 + 0];
                const float x1 = X[(bn0 + r) * 2 + 1];
                s_h[r][t] = x0 * w0 + x1 * w1;
            }
        }
    } else {
        for (int idx = t; idx < 8 * DH; idx += 256)
            s_h[idx >> 7][idx & 127] = h[(size_t)bn0 * DH + idx];
    }
    __syncthreads();

    const float* W = (t < DH) ? Wl : Wr;   // wave-uniform split
    float*       g = (t < DH) ? gl : gr;
    const int f128 = t & 127;
    float acc[8] = {};
    for (int k = 0; k < DH; k += 4) {
        const float w0 = W[(k + 0) * DH + f128];
        const float w1 = W[(k + 1) * DH + f128];
        const float w2 = W[(k + 2) * DH + f128];
        const float w3 = W[(k + 3) * DH + f128];
#pragma unroll
        for (int r = 0; r < 8; ++r) {
            const float4 hv = *(const float4*)&s_h[r][k];
            acc[r] += hv.x * w0 + hv.y * w1 + hv.z * w2 + hv.w * w3;
        }
    }
    const int hh = f128 >> 4, f = f128 & 15;
    float* dst = g + ((size_t)(b * NHEADS + hh) * NN + n0) * NHID + f;
#pragma unroll
    for (int r = 0; r < 8; ++r)
        dst[r * NHID] = acc[r];
}

// ---- flash-style attention: one block per (b, head, 32-row i-tile) ----
// 512 threads: il = t&31 (query row), js = t>>5 (32-j slice).
// gl/gr head slices staged in LDS (64KB); main loop j is wave-uniform
// (2 addrs/wave -> broadcast, free). Online softmax in registers,
// sentinel -1e30 self-heals all-masked prefixes (self-loops guarantee
// every row has >=1 valid edge). Merge scratch aliases dead gl/gr.
__global__ __launch_bounds__(512) void attn_kernel(
    const float* __restrict__ gl, const float* __restrict__ gr,
    const uint32_t* __restrict__ adjb, const float* __restrict__ a_vec,
    float* __restrict__ h_out,
    const float* __restrict__ Wout, float* __restrict__ out)
{
    __shared__ __align__(16) float smem[17504];     // 70016 B -> 2 blocks/CU
    float* s_gl  = smem;                // [512*16]
    float* s_gr  = smem + 8192;         // [512*16]
    float* s_acc = smem;                // alias (dead gl/gr), [16*32*17]=8704
    float* s_m   = smem + 16384;        // [16*33]
    float* s_l   = smem + 16912;        // [16*33]
    float* s_M   = smem + 17440;        // [32]
    float* s_inv = smem + 17472;        // [32]

    const int blk = blockIdx.x;         // 512 = (b*8+hh)*16 + it
    const int it  = blk & 15;
    const int bh  = blk >> 4;
    const int b   = bh >> 3;
    const int hh  = bh & 7;
    const int i0  = it * ITILE;
    const int t   = threadIdx.x;
    const int il  = t & 31;
    const int js  = t >> 5;

    {   // stage head planes: contiguous 32KB each, fully coalesced
        const float4* pgl = (const float4*)(gl + (size_t)bh * NN * NHID);
        const float4* pgr = (const float4*)(gr + (size_t)bh * NN * NHID);
        float4* dl = (float4*)s_gl;
        float4* dr = (float4*)s_gr;
#pragma unroll
        for (int k = 0; k < 4; ++k) {
            dl[k * 512 + t] = pgl[k * 512 + t];
            dr[k * 512 + t] = pgr[k * 512 + t];
        }
    }
    float a[16];
    {
        const float4* pa = (const float4*)a_vec;
#pragma unroll
        for (int q = 0; q < 4; ++q) {
            const float4 v = pa[q];
            a[4*q] = v.x; a[4*q+1] = v.y; a[4*q+2] = v.z; a[4*q+3] = v.w;
        }
    }
    const uint32_t mask = adjb[((size_t)(b * NN + i0 + il)) * 16 + js];
    __syncthreads();

    float gri[16];
    {
        const float4* pr = (const float4*)(s_gr + (i0 + il) * NHID);
#pragma unroll
        for (int q = 0; q < 4; ++q) {
            const float4 v = pr[q];
            gri[4*q] = v.x; gri[4*q+1] = v.y; gri[4*q+2] = v.z; gri[4*q+3] = v.w;
        }
    }

    float m = SENTINEL, l = 0.f;
    float acc[16];
#pragma unroll
    for (int f = 0; f < 16; ++f) acc[f] = 0.f;

    const int jbase = js * 32;
    for (int jc = 0; jc < 32; jc += 4) {
        float sc[4];
#pragma unroll
        for (int k = 0; k < 4; ++k) {
            const int jj = jc + k;
            const float4* pg = (const float4*)(s_gl + (jbase + jj) * NHID);
            float s = 0.f;
#pragma unroll
            for (int q = 0; q < 4; ++q) {
                const float4 g = pg[q];     // wave-uniform j -> broadcast
                float v;
                v = g.x + gri[4*q+0]; v = fmaxf(v, SLOPE * v); s += v * a[4*q+0];
                v = g.y + gri[4*q+1]; v = fmaxf(v, SLOPE * v); s += v * a[4*q+1];
                v = g.z + gri[4*q+2]; v = fmaxf(v, SLOPE * v); s += v * a[4*q+2];
                v = g.w + gri[4*q+3]; v = fmaxf(v, SLOPE * v); s += v * a[4*q+3];
            }
            sc[k] = ((mask >> jj) & 1u) ? s : SENTINEL;
        }
        const float m4   = fmaxf(fmaxf(sc[0], sc[1]), fmaxf(sc[2], sc[3]));
        const float newm = fmaxf(m, m4);
        const float corr = __expf(m - newm);    // ==1 when no new max
        l *= corr;
#pragma unroll
        for (int f = 0; f < 16; ++f) acc[f] *= corr;
        float p[4];
#pragma unroll
        for (int k = 0; k < 4; ++k) p[k] = __expf(sc[k] - newm);  // masked -> 0
        l += p[0] + p[1] + p[2] + p[3];
#pragma unroll
        for (int k = 0; k < 4; ++k) {
            const float4* pg = (const float4*)(s_gr + (jbase + jc + k) * NHID);
#pragma unroll
            for (int q = 0; q < 4; ++q) {
                const float4 g = pg[q];     // broadcast
                acc[4*q+0] += p[k] * g.x; acc[4*q+1] += p[k] * g.y;
                acc[4*q+2] += p[k] * g.z; acc[4*q+3] += p[k] * g.w;
            }
        }
        m = newm;
    }

    s_m[js * 33 + il] = m;
    s_l[js * 33 + il] = l;
    __syncthreads();                     // also retires all gl/gr LDS reads

    if (t < 32) {                        // per-i global max + denom
        float M = SENTINEL;
#pragma unroll
        for (int k = 0; k < 16; ++k) M = fmaxf(M, s_m[k * 33 + t]);
        float L = 0.f;
#pragma unroll
        for (int k = 0; k < 16; ++k) L += s_l[k * 33 + t] * __expf(s_m[k * 33 + t] - M);
        s_M[t]   = M;
        s_inv[t] = 1.f / L;
    }
    __syncthreads();

    {   // scaled partials into aliased scratch (stride 17 -> conflict-free)
        const float scale = __expf(m - s_M[il]) * s_inv[il];
        float* dst = s_acc + (js * 32 + il) * 17;
#pragma unroll
        for (int f = 0; f < 16; ++f) dst[f] = acc[f] * scale;
    }
    __syncthreads();

    {   // final reduce: thread (i = t>>4, f = t&15)
        const int i = t >> 4, f = t & 15;
        float o = 0.f;
#pragma unroll
        for (int k = 0; k < 16; ++k) o += s_acc[(k * 32 + i) * 17 + f];
        if (Wout) {                      // fused h @ W_out partial per head
            float v = o * Wout[hh * NHID + f];
#pragma unroll
            for (int off = 8; off; off >>= 1) v += __shfl_xor(v, off);
            if (f == 0) atomicAdd(out + b * NN + i0 + i, v);
        } else {
            h_out[((size_t)(b * NN + i0 + i)) * DH + hh * NHID + f] = o;
        }
    }
}

extern "C" void kernel_launch(void* const* d_in, const int* in_sizes, int n_in,
                              void* d_out, int out_size, void* d_ws, size_t ws_size,
                              hipStream_t stream) {
    const float* X    = (const float*)d_in[0];   // [4,512,2]
    const int*   adj  = (const int*)  d_in[1];   // [4,512,512]
    const float* Win  = (const float*)d_in[2];   // [2,128]
    const float* Wl   = (const float*)d_in[3];   // [3,128,128]
    const float* Wr   = (const float*)d_in[4];   // [3,128,128]
    const float* Aa   = (const float*)d_in[5];   // [3,16]
    const float* Wout = (const float*)d_in[6];   // [128,1]
    float* out = (float*)d_out;                  // [4,512] fp32

    float*    ws   = (float*)d_ws;
    float*    h    = ws;                 // 1 MB
    float*    gl   = ws + 262144;        // 1 MB (head-major)
    float*    gr   = ws + 524288;        // 1 MB (head-major)
    uint32_t* adjb = (uint32_t*)(ws + 786432);   // 128 KB

    pack_adj_kernel<<<NB * NN / 16, 256, 0, stream>>>(adj, adjb);
    hipMemsetAsync(out, 0, (size_t)out_size * sizeof(float), stream);  // atomic target

    for (int l = 0; l < 3; ++l) {
        proj_kernel<<<NB * NN / 8, 256, 0, stream>>>(
            h, (l == 0) ? X : nullptr, Win,
            Wl + (size_t)l * DH * DH, Wr + (size_t)l * DH * DH, gl, gr);
        const bool last = (l == 2);
        attn_kernel<<<NB * NHEADS * (NN / ITILE), 512, 0, stream>>>(
            gl, gr, adjb, Aa + l * NHID, h,
            last ? Wout : nullptr, out);
    }
}